// Round 1
// baseline (540.050 us; speedup 1.0000x reference)
//
#include <hip/hip_runtime.h>
#include <hip/hip_bf16.h>

// out[bt,o] = b[o] + sum_{i,j in [0,257)} Xa[bt,i]*Xb[bt,j]*W[o, i*257+j]
// Xa = [1, X[bt,:]], Xb = [1, X_aux[bt,:]]
// K split into 258 chunks of 256:
//   c<256 : A[r,j] = X[r,c]*X_aux[r,j], Bp[c][o][j] = W[o,(c+1)*257+1+j]
//   c=256 : A[r,j] = X_aux[r,j],       Bp[c][o][j] = W[o,1+j]
//   c=257 : A[r,j] = X[r,j],           Bp[c][o][j] = W[o,(j+1)*257]
// remaining k=0 term (W[o,0]*1*1) folded into reduce/init with bias.

#define DI 66049
#define SPLIT 4

typedef __attribute__((ext_vector_type(8))) short bf16x8;
typedef __attribute__((ext_vector_type(4))) float f32x4;

__device__ __forceinline__ unsigned short f2b(float f) {
  union { __hip_bfloat16 h; unsigned short u; } cv;
  cv.h = __float2bfloat16(f);
  return cv.u;
}

__device__ __forceinline__ void gload16(const void* g, void* l) {
  __builtin_amdgcn_global_load_lds(
      (const __attribute__((address_space(1))) unsigned int*)g,
      (__attribute__((address_space(3))) unsigned int*)l, 16, 0, 0);
}

// ---- prep: gather W (f32) into bf16 Bp[c][o][j], c in [0,258), o,j in [0,256)
__global__ void prep_w(const float* __restrict__ W, unsigned short* __restrict__ Bp) {
  const int c = blockIdx.x;                       // 0..257
  const int o = (blockIdx.y << 2) + (threadIdx.x >> 6);
  const int j = (threadIdx.x & 63) << 2;          // 4 elems per thread
  const float* wrow = W + (size_t)o * DI;
  float v0, v1, v2, v3;
  if (c < 256) {
    const int bse = (c + 1) * 257 + 1 + j;
    v0 = wrow[bse]; v1 = wrow[bse + 1]; v2 = wrow[bse + 2]; v3 = wrow[bse + 3];
  } else if (c == 256) {
    const int bse = 1 + j;
    v0 = wrow[bse]; v1 = wrow[bse + 1]; v2 = wrow[bse + 2]; v3 = wrow[bse + 3];
  } else {
    v0 = wrow[(j + 1) * 257]; v1 = wrow[(j + 2) * 257];
    v2 = wrow[(j + 3) * 257]; v3 = wrow[(j + 4) * 257];
  }
  unsigned short* dst = Bp + (((size_t)c << 8) + o) * 256 + j;
  const unsigned int lo = (unsigned int)f2b(v0) | ((unsigned int)f2b(v1) << 16);
  const unsigned int hi = (unsigned int)f2b(v2) | ((unsigned int)f2b(v3) << 16);
  *(uint2*)dst = make_uint2(lo, hi);
}

// ---- main GEMM: 128x128 tile, 4 waves (64x64 each), BK=64, 16x16x32 bf16 MFMA
template <bool PREPPED, bool ATOMIC>
__global__ __launch_bounds__(256, 2) void gemm_k(
    const float* __restrict__ X, const float* __restrict__ Xa,
    const float* __restrict__ W, const unsigned short* __restrict__ Bp,
    float* __restrict__ OutP) {
  constexpr int BST = PREPPED ? 64 : 72;  // Bs row stride (elements)
  __shared__ __align__(16) unsigned short As[128 * 72];
  __shared__ __align__(16) unsigned short Bs[128 * BST];

  const int tid = threadIdx.x;
  const int bx = blockIdx.x;   // 32 m-tiles
  const int by = blockIdx.y;   // 2 n-tiles
  const int bz = blockIdx.z;   // SPLIT
  const int bt0 = bx << 7, o0 = by << 7;
  const int c0 = bz * 64 + (bz < 2 ? bz : 2);
  const int ccnt = 64 + (bz < 2 ? 1 : 0);   // 65,65,64,64 -> 258
  const int nK = ccnt << 2;

  const int wid = tid >> 6, lane = tid & 63;
  const int wr = (wid >> 1) << 6, wc = (wid & 1) << 6;

  const int ar = tid >> 1;            // A row 0..127
  const int ah = (tid & 1) << 5;      // j-half 0/32
  const float* xrow  = X  + (size_t)(bt0 + ar) * 256;
  const float* varow = Xa + (size_t)(bt0 + ar) * 256;

  f32x4 acc[4][4] = {};

  for (int kt = 0; kt < nK; ++kt) {
    const int c = c0 + (kt >> 2);
    const int j0 = (kt & 3) << 6;

    __syncthreads();

    // ---- stage A: As[r][jj] = s * V[r, j0+jj]  (bf16)
    {
      const float* vs = (c == 257) ? xrow : varow;
      float s = 1.0f;
      if (c < 256) s = xrow[c];
      const f32x4* vp = (const f32x4*)(vs + j0 + ah);
      f32x4 v[8];
#pragma unroll
      for (int q = 0; q < 8; ++q) v[q] = vp[q];
      unsigned short* aw = As + ar * 72 + ah;
#pragma unroll
      for (int w = 0; w < 4; ++w) {
        bf16x8 pk;
#pragma unroll
        for (int e = 0; e < 8; ++e)
          pk[e] = (short)f2b(s * v[w * 2 + (e >> 2)][e & 3]);
        *(bf16x8*)(aw + w * 8) = pk;
      }
    }

    // ---- stage B
    if (PREPPED) {
#pragma unroll
      for (int q = 0; q < 4; ++q) {
        const int cb = (q << 2) + wid;                  // 16 chunks of 1 KiB
        const int orow = (cb << 3) + (lane >> 3);
        const unsigned short* src =
            Bp + (((size_t)c * 256 + o0 + orow) << 8) + j0 + ((lane & 7) << 3);
        gload16(src, Bs + (cb << 9));
      }
    } else {
      const int orow = tid >> 1;
      const int jh = (tid & 1) << 5;
      const float* wrow = W + (size_t)(o0 + orow) * DI;
      float tmp[32];
      if (c < 256) {
        const int bse = (c + 1) * 257 + 1 + j0 + jh;
#pragma unroll
        for (int i = 0; i < 32; ++i) tmp[i] = wrow[bse + i];
      } else if (c == 256) {
        const int bse = 1 + j0 + jh;
#pragma unroll
        for (int i = 0; i < 32; ++i) tmp[i] = wrow[bse + i];
      } else {
#pragma unroll
        for (int i = 0; i < 32; ++i) tmp[i] = wrow[(j0 + jh + i + 1) * 257];
      }
      unsigned short* bw = Bs + orow * BST + jh;
#pragma unroll
      for (int w = 0; w < 4; ++w) {
        bf16x8 pk;
#pragma unroll
        for (int e = 0; e < 8; ++e) pk[e] = (short)f2b(tmp[w * 8 + e]);
        *(bf16x8*)(bw + w * 8) = pk;
      }
    }

    __syncthreads();

    // ---- compute
#pragma unroll
    for (int kk = 0; kk < 2; ++kk) {
      const int ko = (kk << 5) + ((lane >> 4) << 3);
      bf16x8 af[4], bfr[4];
#pragma unroll
      for (int fm = 0; fm < 4; ++fm)
        af[fm] = *(const bf16x8*)(As + (wr + (fm << 4) + (lane & 15)) * 72 + ko);
#pragma unroll
      for (int fn = 0; fn < 4; ++fn)
        bfr[fn] = *(const bf16x8*)(Bs + (wc + (fn << 4) + (lane & 15)) * BST + ko);
#pragma unroll
      for (int fm = 0; fm < 4; ++fm)
#pragma unroll
        for (int fn = 0; fn < 4; ++fn)
          acc[fm][fn] = __builtin_amdgcn_mfma_f32_16x16x32_bf16(
              af[fm], bfr[fn], acc[fm][fn], 0, 0, 0);
    }
  }

  // ---- epilogue (C layout: col = lane&15, row = (lane>>4)*4 + reg)
  const int r0 = (lane >> 4) << 2;
  const int cl = lane & 15;
  if (ATOMIC) {
#pragma unroll
    for (int fm = 0; fm < 4; ++fm) {
      const int row = bt0 + wr + (fm << 4) + r0;
#pragma unroll
      for (int fn = 0; fn < 4; ++fn) {
        const int col = o0 + wc + (fn << 4) + cl;
#pragma unroll
        for (int r = 0; r < 4; ++r)
          atomicAdd(OutP + (size_t)(row + r) * 256 + col, acc[fm][fn][r]);
      }
    }
  } else {
    float* pp = OutP + (size_t)bz * (4096 * 256);
#pragma unroll
    for (int fm = 0; fm < 4; ++fm) {
      const int row = bt0 + wr + (fm << 4) + r0;
#pragma unroll
      for (int fn = 0; fn < 4; ++fn) {
        const int col = o0 + wc + (fn << 4) + cl;
#pragma unroll
        for (int r = 0; r < 4; ++r)
          pp[(size_t)(row + r) * 256 + col] = acc[fm][fn][r];
      }
    }
  }
}

// ---- reduce split-K partials + bias + W[o,0]
__global__ void reduce_k(const float* __restrict__ P, const float* __restrict__ W,
                         const float* __restrict__ b, float* __restrict__ out) {
  const int idx = blockIdx.x * 256 + threadIdx.x;
  const int o = idx & 255;
  float v = b[o] + W[(size_t)o * DI];
  v += P[idx];
  v += P[idx + 1048576];
  v += P[idx + 2097152];
  v += P[idx + 3145728];
  out[idx] = v;
}

// ---- init for atomic fallback
__global__ void init_k(const float* __restrict__ W, const float* __restrict__ b,
                       float* __restrict__ out) {
  const int idx = blockIdx.x * 256 + threadIdx.x;
  const int o = idx & 255;
  out[idx] = b[o] + W[(size_t)o * DI];
}

extern "C" void kernel_launch(void* const* d_in, const int* in_sizes, int n_in,
                              void* d_out, int out_size, void* d_ws, size_t ws_size,
                              hipStream_t stream) {
  const float* X  = (const float*)d_in[0];
  const float* Xa = (const float*)d_in[1];
  const float* W  = (const float*)d_in[2];
  const float* b  = (const float*)d_in[3];
  float* out = (float*)d_out;

  const size_t WBF_SZ  = (size_t)258 * 256 * 256 * 2;   // 33,816,576 B
  const size_t PART_SZ = (size_t)SPLIT * 4096 * 256 * 4; // 16,777,216 B

  if (ws_size >= WBF_SZ + PART_SZ) {
    unsigned short* Bp = (unsigned short*)d_ws;
    float* P = (float*)((char*)d_ws + WBF_SZ);
    prep_w<<<dim3(258, 64), 256, 0, stream>>>(W, Bp);
    gemm_k<true, false><<<dim3(32, 2, SPLIT), 256, 0, stream>>>(X, Xa, W, Bp, P);
    reduce_k<<<4096, 256, 0, stream>>>(P, W, b, out);
  } else {
    init_k<<<4096, 256, 0, stream>>>(W, b, out);
    gemm_k<false, true><<<dim3(32, 2, SPLIT), 256, 0, stream>>>(X, Xa, W, nullptr, out);
  }
}

// Round 2
// 419.582 us; speedup vs baseline: 1.2871x; 1.2871x over previous
//
#include <hip/hip_runtime.h>
#include <hip/hip_bf16.h>

// out[bt,o] = b[o] + sum_{i,j in [0,257)} Xa[bt,i]*Xb[bt,j]*W[o, i*257+j]
// Xa = [1, X[bt,:]], Xb = [1, X_aux[bt,:]]
// K split into 258 chunks of 256:
//   c<256 : A[r,j] = X[r,c]*X_aux[r,j], Bp[c][o][j] = W[o,(c+1)*257+1+j]
//   c=256 : A[r,j] = X_aux[r,j],       Bp[c][o][j] = W[o,1+j]
//   c=257 : A[r,j] = X[r,j],           Bp[c][o][j] = W[o,(j+1)*257]
// k=0 term (W[o,0]) folded into reduce/init with bias.
//
// R2: split-K 4->16 (adaptive) for 4 blocks/CU occupancy; XOR 16B-slot
// swizzle on As and Bs (Bs via pre-swizzled per-lane global source since
// global_load_lds writes linearly).

#define DI 66049

typedef __attribute__((ext_vector_type(8))) short bf16x8;
typedef __attribute__((ext_vector_type(4))) float f32x4;

__device__ __forceinline__ unsigned short f2b(float f) {
  union { __hip_bfloat16 h; unsigned short u; } cv;
  cv.h = __float2bfloat16(f);
  return cv.u;
}

__device__ __forceinline__ void gload16(const void* g, void* l) {
  __builtin_amdgcn_global_load_lds(
      (const __attribute__((address_space(1))) unsigned int*)g,
      (__attribute__((address_space(3))) unsigned int*)l, 16, 0, 0);
}

// ---- prep: gather W (f32) into bf16 Bp[c][o][j] (linear layout)
__global__ void prep_w(const float* __restrict__ W, unsigned short* __restrict__ Bp) {
  const int c = blockIdx.x;                       // 0..257
  const int o = (blockIdx.y << 2) + (threadIdx.x >> 6);
  const int j = (threadIdx.x & 63) << 2;          // 4 elems per thread
  const float* wrow = W + (size_t)o * DI;
  float v0, v1, v2, v3;
  if (c < 256) {
    const int bse = (c + 1) * 257 + 1 + j;
    v0 = wrow[bse]; v1 = wrow[bse + 1]; v2 = wrow[bse + 2]; v3 = wrow[bse + 3];
  } else if (c == 256) {
    const int bse = 1 + j;
    v0 = wrow[bse]; v1 = wrow[bse + 1]; v2 = wrow[bse + 2]; v3 = wrow[bse + 3];
  } else {
    v0 = wrow[(j + 1) * 257]; v1 = wrow[(j + 2) * 257];
    v2 = wrow[(j + 3) * 257]; v3 = wrow[(j + 4) * 257];
  }
  unsigned short* dst = Bp + (((size_t)c << 8) + o) * 256 + j;
  const unsigned int lo = (unsigned int)f2b(v0) | ((unsigned int)f2b(v1) << 16);
  const unsigned int hi = (unsigned int)f2b(v2) | ((unsigned int)f2b(v3) << 16);
  *(uint2*)dst = make_uint2(lo, hi);
}

// ---- main GEMM: 128x128 tile, 4 waves (64x64 each), BK=64, 16x16x32 bf16 MFMA
// LDS layout: [row][slot^ (row&7)][8 shorts], row stride 64 shorts (128B).
template <bool PREPPED, bool ATOMIC>
__global__ __launch_bounds__(256, 4) void gemm_k(
    const float* __restrict__ X, const float* __restrict__ Xa,
    const float* __restrict__ W, const unsigned short* __restrict__ Bp,
    float* __restrict__ OutP) {
  __shared__ __align__(16) unsigned short As[128 * 64];
  __shared__ __align__(16) unsigned short Bs[128 * 64];

  const int tid = threadIdx.x;
  const int bx = blockIdx.x;   // 32 m-tiles
  const int by = blockIdx.y;   // 2 n-tiles
  const int bz = blockIdx.z;   // split-K
  const int S = gridDim.z;
  const int bt0 = bx << 7, o0 = by << 7;
  const int q = 258 / S, r = 258 % S;
  const int c0 = bz * q + (bz < r ? bz : r);
  const int ccnt = q + (bz < r ? 1 : 0);
  const int nK = ccnt << 2;

  const int wid = tid >> 6, lane = tid & 63;
  const int wr = (wid >> 1) << 6, wc = (wid & 1) << 6;

  const int ar = tid >> 1;            // A row 0..127
  const int ah = (tid & 1) << 5;      // j-half 0/32 (shorts)
  const float* xrow  = X  + (size_t)(bt0 + ar) * 256;
  const float* varow = Xa + (size_t)(bt0 + ar) * 256;

  f32x4 acc[4][4] = {};

  for (int kt = 0; kt < nK; ++kt) {
    const int c = c0 + (kt >> 2);
    const int j0 = (kt & 3) << 6;

    __syncthreads();

    // ---- stage A: As[r][jj] = s * V[r, j0+jj] (bf16), XOR-swizzled slots
    {
      const float* vs = (c == 257) ? xrow : varow;
      float s = 1.0f;
      if (c < 256) s = xrow[c];
      const f32x4* vp = (const f32x4*)(vs + j0 + ah);
      f32x4 v[8];
#pragma unroll
      for (int qq = 0; qq < 8; ++qq) v[qq] = vp[qq];
      unsigned short* aw = As + ar * 64;
      const int sl0 = ah >> 3;          // logical slot base (0 or 4)
      const int sx = ar & 7;
#pragma unroll
      for (int w = 0; w < 4; ++w) {
        bf16x8 pk;
#pragma unroll
        for (int e = 0; e < 8; ++e)
          pk[e] = (short)f2b(s * v[w * 2 + (e >> 2)][e & 3]);
        *(bf16x8*)(aw + (((sl0 + w) ^ sx) << 3)) = pk;
      }
    }

    // ---- stage B
    if (PREPPED) {
#pragma unroll
      for (int qq = 0; qq < 4; ++qq) {
        const int cb = (qq << 2) + wid;                 // 16 chunks of 1 KiB
        const int orow = (cb << 3) + (lane >> 3);
        const int slotl = (lane & 7) ^ (orow & 7);      // pre-swizzled source
        const unsigned short* src =
            Bp + (((size_t)c * 256 + o0 + orow) << 8) + j0 + (slotl << 3);
        gload16(src, Bs + (cb << 9));
      }
    } else {
      const int orow = tid >> 1;
      const int jh = (tid & 1) << 5;
      const float* wrow = W + (size_t)(o0 + orow) * DI;
      float tmp[32];
      if (c < 256) {
        const int bse = (c + 1) * 257 + 1 + j0 + jh;
#pragma unroll
        for (int i = 0; i < 32; ++i) tmp[i] = wrow[bse + i];
      } else if (c == 256) {
        const int bse = 1 + j0 + jh;
#pragma unroll
        for (int i = 0; i < 32; ++i) tmp[i] = wrow[bse + i];
      } else {
#pragma unroll
        for (int i = 0; i < 32; ++i) tmp[i] = wrow[(j0 + jh + i + 1) * 257];
      }
      unsigned short* bw = Bs + orow * 64;
      const int sl0 = jh >> 3, sx = orow & 7;
#pragma unroll
      for (int w = 0; w < 4; ++w) {
        bf16x8 pk;
#pragma unroll
        for (int e = 0; e < 8; ++e) pk[e] = (short)f2b(tmp[w * 8 + e]);
        *(bf16x8*)(bw + (((sl0 + w) ^ sx) << 3)) = pk;
      }
    }

    __syncthreads();

    // ---- compute
#pragma unroll
    for (int kk = 0; kk < 2; ++kk) {
      const int kslot = (kk << 2) + (lane >> 4);   // 8-short slot index
      bf16x8 af[4], bfr[4];
#pragma unroll
      for (int fm = 0; fm < 4; ++fm) {
        const int row = wr + (fm << 4) + (lane & 15);
        af[fm] = *(const bf16x8*)(As + row * 64 + ((kslot ^ (row & 7)) << 3));
      }
#pragma unroll
      for (int fn = 0; fn < 4; ++fn) {
        const int row = wc + (fn << 4) + (lane & 15);
        bfr[fn] = *(const bf16x8*)(Bs + row * 64 + ((kslot ^ (row & 7)) << 3));
      }
#pragma unroll
      for (int fm = 0; fm < 4; ++fm)
#pragma unroll
        for (int fn = 0; fn < 4; ++fn)
          acc[fm][fn] = __builtin_amdgcn_mfma_f32_16x16x32_bf16(
              af[fm], bfr[fn], acc[fm][fn], 0, 0, 0);
    }
  }

  // ---- epilogue (C layout: col = lane&15, row = (lane>>4)*4 + reg)
  const int r0 = (lane >> 4) << 2;
  const int cl = lane & 15;
  if (ATOMIC) {
#pragma unroll
    for (int fm = 0; fm < 4; ++fm) {
      const int row = bt0 + wr + (fm << 4) + r0;
#pragma unroll
      for (int fn = 0; fn < 4; ++fn) {
        const int col = o0 + wc + (fn << 4) + cl;
#pragma unroll
        for (int rr = 0; rr < 4; ++rr)
          atomicAdd(OutP + (size_t)(row + rr) * 256 + col, acc[fm][fn][rr]);
      }
    }
  } else {
    float* pp = OutP + (size_t)bz * (4096 * 256);
#pragma unroll
    for (int fm = 0; fm < 4; ++fm) {
      const int row = bt0 + wr + (fm << 4) + r0;
#pragma unroll
      for (int fn = 0; fn < 4; ++fn) {
        const int col = o0 + wc + (fn << 4) + cl;
#pragma unroll
        for (int rr = 0; rr < 4; ++rr)
          pp[(size_t)(row + rr) * 256 + col] = acc[fm][fn][rr];
      }
    }
  }
}

// ---- reduce split-K partials + bias + W[o,0]
__global__ void reduce_k(const float* __restrict__ P, const float* __restrict__ W,
                         const float* __restrict__ b, float* __restrict__ out,
                         int S) {
  const int idx = blockIdx.x * 256 + threadIdx.x;
  const int o = idx & 255;
  float v = b[o] + W[(size_t)o * DI];
  for (int s = 0; s < S; ++s) v += P[idx + (size_t)s * 1048576];
  out[idx] = v;
}

// ---- init for atomic fallback
__global__ void init_k(const float* __restrict__ W, const float* __restrict__ b,
                       float* __restrict__ out) {
  const int idx = blockIdx.x * 256 + threadIdx.x;
  const int o = idx & 255;
  out[idx] = b[o] + W[(size_t)o * DI];
}

extern "C" void kernel_launch(void* const* d_in, const int* in_sizes, int n_in,
                              void* d_out, int out_size, void* d_ws, size_t ws_size,
                              hipStream_t stream) {
  const float* X  = (const float*)d_in[0];
  const float* Xa = (const float*)d_in[1];
  const float* W  = (const float*)d_in[2];
  const float* b  = (const float*)d_in[3];
  float* out = (float*)d_out;

  const size_t WBF_SZ = (size_t)258 * 256 * 256 * 2;    // 33,816,576 B
  const size_t PART1  = (size_t)4096 * 256 * 4;         // 4 MiB per split

  int S = 0;
  for (int cand : {16, 8, 4})
    if (ws_size >= WBF_SZ + (size_t)cand * PART1) { S = cand; break; }

  if (S > 0) {
    unsigned short* Bp = (unsigned short*)d_ws;
    float* P = (float*)((char*)d_ws + WBF_SZ);
    prep_w<<<dim3(258, 64), 256, 0, stream>>>(W, Bp);
    gemm_k<true, false><<<dim3(32, 2, S), 256, 0, stream>>>(X, Xa, W, Bp, P);
    reduce_k<<<4096, 256, 0, stream>>>(P, W, b, out, S);
  } else {
    init_k<<<4096, 256, 0, stream>>>(W, b, out);
    gemm_k<false, true><<<dim3(32, 2, 4), 256, 0, stream>>>(X, Xa, W, nullptr, out);
  }
}